// Round 8
// baseline (3444.606 us; speedup 1.0000x reference)
//
#include <hip/hip_runtime.h>
#include <math.h>

#define Bb 32
#define Nn 128
#define Kk 48
#define Ff 256
#define Gg 50
#define Tt 3

__device__ __forceinline__ float ssp_f(float v) {
    return fmaxf(v, 0.f) + log1pf(expf(-fabsf(v))) - 0.69314718055994530942f;
}

#define LDG4(p) (*reinterpret_cast<const float4*>(p))
#define ST4(p, v) (*reinterpret_cast<float4*>(p) = (v))

// dst[4] += s * vv.{x,y,z,w}   (param must NOT be named like a member!)
#define FMA4(dst, s, vv)                      \
    dst[0] = fmaf((s), (vv).x, dst[0]);       \
    dst[1] = fmaf((s), (vv).y, dst[1]);       \
    dst[2] = fmaf((s), (vv).z, dst[2]);       \
    dst[3] = fmaf((s), (vv).w, dst[3]);

// layer-2 inner block: 6 rows x 8 h-cols with weight array WQ at h-base HH
#define L2BLK(WQ, HH)                                             \
    _Pragma("unroll")                                             \
    for (int rr = 0; rr < 6; ++rr) {                              \
        const float4 s0 = LDG4(&sH[lb + rr][HH]);                 \
        const float4 s1 = LDG4(&sH[lb + rr][(HH) + 4]);           \
        FMA4(acc[rr], s0.x, WQ[0]); FMA4(acc[rr], s0.y, WQ[1]);   \
        FMA4(acc[rr], s0.z, WQ[2]); FMA4(acc[rr], s0.w, WQ[3]);   \
        FMA4(acc[rr], s1.x, WQ[4]); FMA4(acc[rr], s1.y, WQ[5]);   \
        FMA4(acc[rr], s1.z, WQ[6]); FMA4(acc[rr], s1.w, WQ[7]);   \
    }

// ---------------------------------------------------------------------------
// k_setup: x = embedding[z]; d, fexp, fcut per (b,n,k)
// ---------------------------------------------------------------------------
__global__ __launch_bounds__(256) void k_setup(
    const float* __restrict__ pos, const int* __restrict__ zz,
    const int* __restrict__ nbr, const float* __restrict__ nmask,
    const float* __restrict__ emb,
    float* __restrict__ x, float* __restrict__ fexp, float* __restrict__ fcut)
{
    const int bn = blockIdx.x;
    const int b  = bn >> 7;
    const int t  = threadIdx.x;
    __shared__ float sd[Kk];

    x[bn * Ff + t] = emb[zz[bn] * Ff + t];

    if (t < Kk) {
        int j = nbr[bn * Kk + t];
        float px = pos[bn * 3 + 0], py = pos[bn * 3 + 1], pz = pos[bn * 3 + 2];
        int rj = (b * Nn + j) * 3;
        float dx = pos[rj + 0] - px;
        float dy = pos[rj + 1] - py;
        float dz = pos[rj + 2] - pz;
        float d = sqrtf(fmaf(dx, dx, fmaf(dy, dy, dz * dz)) + 1e-8f);
        sd[t] = d;
        float fc = 0.5f * (cosf(3.14159265358979323846f * d / 5.0f) + 1.0f);
        fc = (d < 5.0f) ? fc : 0.0f;
        fcut[bn * Kk + t] = fc * nmask[bn * Kk + t];
    }
    __syncthreads();

    const float step = 5.0f / 49.0f;
    const float coeff = -0.5f / (step * step);
    for (int i = t; i < Kk * Gg; i += 256) {
        int k = i / Gg, g = i - k * Gg;
        float dd = sd[k] - step * (float)g;
        fexp[bn * (Kk * Gg) + i] = expf(coeff * dd * dd);
    }
}

// ---------------------------------------------------------------------------
// k_y4: y = x @ in2f_w[t] for 4 atoms per block (w read once per 4 atoms)
// ---------------------------------------------------------------------------
__global__ __launch_bounds__(256) void k_y4(
    const float* __restrict__ x, const float* __restrict__ w,
    float* __restrict__ y)
{
    const int bn0 = blockIdx.x * 4;
    const int tid = threadIdx.x;
    const int tx  = tid & 63;
    const int ty  = tid >> 6;
    const int f4  = tx * 4;

    __shared__ __align__(16) float sx[4][Ff];        // 4 KB
    __shared__ __align__(16) float p4s[4][4][Ff];    // 16 KB [ty][atom][f]

    #pragma unroll
    for (int a = 0; a < 4; ++a)
        sx[a][tid] = x[(bn0 + a) * Ff + tid];
    __syncthreads();

    float p0[4] = {0.f, 0.f, 0.f, 0.f};
    float p1[4] = {0.f, 0.f, 0.f, 0.f};
    float p2[4] = {0.f, 0.f, 0.f, 0.f};
    float p3[4] = {0.f, 0.f, 0.f, 0.f};

    #pragma unroll 1
    for (int hh = 0; hh < 64; hh += 8) {
        const int h0 = ty * 64 + hh;
        float4 wq[8];
        #pragma unroll
        for (int j = 0; j < 8; ++j)
            wq[j] = LDG4(&w[(h0 + j) * Ff + f4]);

        {
            const float4 a0 = LDG4(&sx[0][h0]);
            const float4 a1 = LDG4(&sx[0][h0 + 4]);
            FMA4(p0, a0.x, wq[0]); FMA4(p0, a0.y, wq[1]);
            FMA4(p0, a0.z, wq[2]); FMA4(p0, a0.w, wq[3]);
            FMA4(p0, a1.x, wq[4]); FMA4(p0, a1.y, wq[5]);
            FMA4(p0, a1.z, wq[6]); FMA4(p0, a1.w, wq[7]);
        }
        {
            const float4 a0 = LDG4(&sx[1][h0]);
            const float4 a1 = LDG4(&sx[1][h0 + 4]);
            FMA4(p1, a0.x, wq[0]); FMA4(p1, a0.y, wq[1]);
            FMA4(p1, a0.z, wq[2]); FMA4(p1, a0.w, wq[3]);
            FMA4(p1, a1.x, wq[4]); FMA4(p1, a1.y, wq[5]);
            FMA4(p1, a1.z, wq[6]); FMA4(p1, a1.w, wq[7]);
        }
        {
            const float4 a0 = LDG4(&sx[2][h0]);
            const float4 a1 = LDG4(&sx[2][h0 + 4]);
            FMA4(p2, a0.x, wq[0]); FMA4(p2, a0.y, wq[1]);
            FMA4(p2, a0.z, wq[2]); FMA4(p2, a0.w, wq[3]);
            FMA4(p2, a1.x, wq[4]); FMA4(p2, a1.y, wq[5]);
            FMA4(p2, a1.z, wq[6]); FMA4(p2, a1.w, wq[7]);
        }
        {
            const float4 a0 = LDG4(&sx[3][h0]);
            const float4 a1 = LDG4(&sx[3][h0 + 4]);
            FMA4(p3, a0.x, wq[0]); FMA4(p3, a0.y, wq[1]);
            FMA4(p3, a0.z, wq[2]); FMA4(p3, a0.w, wq[3]);
            FMA4(p3, a1.x, wq[4]); FMA4(p3, a1.y, wq[5]);
            FMA4(p3, a1.z, wq[6]); FMA4(p3, a1.w, wq[7]);
        }
    }
    ST4(&p4s[ty][0][f4], make_float4(p0[0], p0[1], p0[2], p0[3]));
    ST4(&p4s[ty][1][f4], make_float4(p1[0], p1[1], p1[2], p1[3]));
    ST4(&p4s[ty][2][f4], make_float4(p2[0], p2[1], p2[2], p2[3]));
    ST4(&p4s[ty][3][f4], make_float4(p3[0], p3[1], p3[2], p3[3]));
    __syncthreads();

    #pragma unroll
    for (int a = 0; a < 4; ++a)
        y[(bn0 + a) * Ff + tid] = p4s[0][a][tid] + p4s[1][a][tid]
                                + p4s[2][a][tid] + p4s[3][a][tid];
}

// ---------------------------------------------------------------------------
// k_agg4: one atom per block, K in 2 passes of 24 rows -> 37.4 KB LDS,
// 4 blocks/CU. Waves split F; lanes: kq = lane>>4, fq = lane&15.
// launch_bounds min-waves = 3 so regalloc targets ~170 (NOT 64 -> no spills).
// Layer-2 weight loads double-buffered in registers (issue-early, T14).
// ---------------------------------------------------------------------------
__global__ __launch_bounds__(256, 3) void k_agg4(
    const float* __restrict__ fexp, const float* __restrict__ fcut,
    const int* __restrict__ nbr, const float* __restrict__ y,
    const float* __restrict__ w1, const float* __restrict__ b1,
    const float* __restrict__ w2, const float* __restrict__ b2,
    const float* __restrict__ fw1, const float* __restrict__ fb1,
    const float* __restrict__ fw2, const float* __restrict__ fb2,
    float* __restrict__ x)
{
    const int bn    = blockIdx.x;
    const int bbase = (bn >> 7) << 7;       // b * 128
    const int tid   = threadIdx.x;
    const int w     = tid >> 6;
    const int lane  = tid & 63;
    const int kq    = lane >> 4;            // 0..3
    const int fq    = lane & 15;            // 0..15
    const int fbase = w * 64 + fq * 4;
    const int lb    = kq * 6;               // local sH row base (per pass)

    __shared__ __align__(16) float sH[24][260];   // 24960 B (pass-local H)
    __shared__ __align__(16) float sfe[Kk][52];   // 9984 B
    __shared__ __align__(16) float agg_s[Ff];     // 1 KB
    __shared__ __align__(16) float sv_s[Ff];      // 1 KB
    __shared__ float scut[Kk];
    __shared__ int   snbr[Kk];

    // ---- coop loads ----
    for (int idx = tid; idx < Kk * Gg; idx += 256) {
        int r = idx / Gg, g = idx - r * Gg;
        sfe[r][g] = fexp[bn * (Kk * Gg) + idx];
    }
    if (tid < Kk) {
        scut[tid] = fcut[bn * Kk + tid];
        snbr[tid] = nbr[bn * Kk + tid];
    }
    __syncthreads();

    const float4 b1q = LDG4(&b1[fbase]);
    const float4 b2q = LDG4(&b2[fbase]);
    float aggp[4] = {0.f, 0.f, 0.f, 0.f};

    #pragma unroll 1
    for (int pass = 0; pass < 2; ++pass) {
        const int kb = pass * 24 + kq * 6;  // this thread's global k start

        // ---- filter layer 1: 6 rows ----
        float h1[6][4];
        #pragma unroll
        for (int rr = 0; rr < 6; ++rr) {
            h1[rr][0] = b1q.x; h1[rr][1] = b1q.y;
            h1[rr][2] = b1q.z; h1[rr][3] = b1q.w;
        }
        #pragma unroll 1
        for (int c = 0; c < 6; ++c) {
            const int g0 = c * 8;
            float4 wq[8];
            #pragma unroll
            for (int j = 0; j < 8; ++j)
                wq[j] = LDG4(&w1[(g0 + j) * Ff + fbase]);
            #pragma unroll
            for (int rr = 0; rr < 6; ++rr) {
                const float4 fe0 = LDG4(&sfe[kb + rr][g0]);
                const float4 fe1 = LDG4(&sfe[kb + rr][g0 + 4]);
                FMA4(h1[rr], fe0.x, wq[0]); FMA4(h1[rr], fe0.y, wq[1]);
                FMA4(h1[rr], fe0.z, wq[2]); FMA4(h1[rr], fe0.w, wq[3]);
                FMA4(h1[rr], fe1.x, wq[4]); FMA4(h1[rr], fe1.y, wq[5]);
                FMA4(h1[rr], fe1.z, wq[6]); FMA4(h1[rr], fe1.w, wq[7]);
            }
        }
        {
            const float4 wt0 = LDG4(&w1[48 * Ff + fbase]);
            const float4 wt1 = LDG4(&w1[49 * Ff + fbase]);
            #pragma unroll
            for (int rr = 0; rr < 6; ++rr) {
                const float fa = sfe[kb + rr][48];
                const float fb = sfe[kb + rr][49];
                FMA4(h1[rr], fa, wt0);
                FMA4(h1[rr], fb, wt1);
                float4 hv;
                hv.x = ssp_f(h1[rr][0]); hv.y = ssp_f(h1[rr][1]);
                hv.z = ssp_f(h1[rr][2]); hv.w = ssp_f(h1[rr][3]);
                ST4(&sH[lb + rr][fbase], hv);
            }
        }
        __syncthreads();

        // ---- filter layer 2: 6 rows x full h, reg-double-buffered weights ----
        float acc[6][4];
        #pragma unroll
        for (int rr = 0; rr < 6; ++rr) {
            acc[rr][0] = 0.f; acc[rr][1] = 0.f;
            acc[rr][2] = 0.f; acc[rr][3] = 0.f;
        }
        {
            float4 wqa[8], wqb[8];
            #pragma unroll
            for (int j = 0; j < 8; ++j)
                wqa[j] = LDG4(&w2[j * Ff + fbase]);

            #pragma unroll 1
            for (int cc = 0; cc < 16; ++cc) {
                const int hA = cc * 16;
                const int hB = hA + 8;
                #pragma unroll
                for (int j = 0; j < 8; ++j)
                    wqb[j] = LDG4(&w2[(hB + j) * Ff + fbase]);
                L2BLK(wqa, hA);
                if (cc < 15) {
                    #pragma unroll
                    for (int j = 0; j < 8; ++j)
                        wqa[j] = LDG4(&w2[(hA + 16 + j) * Ff + fbase]);
                }
                L2BLK(wqb, hB);
            }
        }

        // ---- cutoff + neighbor y gather (this pass's 6 rows) ----
        #pragma unroll
        for (int rr = 0; rr < 6; ++rr) {
            const float ct = scut[kb + rr];
            const int   nb = snbr[kb + rr];
            const float4 yv = LDG4(&y[(bbase + nb) * Ff + fbase]);
            aggp[0] = fmaf((acc[rr][0] + b2q.x) * ct, yv.x, aggp[0]);
            aggp[1] = fmaf((acc[rr][1] + b2q.y) * ct, yv.y, aggp[1]);
            aggp[2] = fmaf((acc[rr][2] + b2q.z) * ct, yv.z, aggp[2]);
            aggp[3] = fmaf((acc[rr][3] + b2q.w) * ct, yv.w, aggp[3]);
        }
        __syncthreads();   // before next pass overwrites sH
    }

    // in-register reduce across kq (lane bits 4,5)
    #pragma unroll
    for (int j = 0; j < 4; ++j) {
        aggp[j] += __shfl_xor(aggp[j], 16);
        aggp[j] += __shfl_xor(aggp[j], 32);
    }
    if (kq == 0)
        ST4(&agg_s[fbase], make_float4(aggp[0], aggp[1], aggp[2], aggp[3]));
    __syncthreads();

    // ---- f2out matvec 1: kq reinterpreted as h-quarter ----
    {
        float p[4] = {0.f, 0.f, 0.f, 0.f};
        const int hb = kq * 64;
        #pragma unroll 1
        for (int c = 0; c < 8; ++c) {
            const int h0 = hb + c * 8;
            float4 wq[8];
            #pragma unroll
            for (int j = 0; j < 8; ++j)
                wq[j] = LDG4(&fw1[(h0 + j) * Ff + fbase]);
            const float4 a0 = LDG4(&agg_s[h0]);
            const float4 a1 = LDG4(&agg_s[h0 + 4]);
            FMA4(p, a0.x, wq[0]); FMA4(p, a0.y, wq[1]);
            FMA4(p, a0.z, wq[2]); FMA4(p, a0.w, wq[3]);
            FMA4(p, a1.x, wq[4]); FMA4(p, a1.y, wq[5]);
            FMA4(p, a1.z, wq[6]); FMA4(p, a1.w, wq[7]);
        }
        #pragma unroll
        for (int j = 0; j < 4; ++j) {
            p[j] += __shfl_xor(p[j], 16);
            p[j] += __shfl_xor(p[j], 32);
        }
        if (kq == 0) {
            const float4 fb1q = LDG4(&fb1[fbase]);
            float4 sv;
            sv.x = ssp_f(p[0] + fb1q.x); sv.y = ssp_f(p[1] + fb1q.y);
            sv.z = ssp_f(p[2] + fb1q.z); sv.w = ssp_f(p[3] + fb1q.w);
            ST4(&sv_s[fbase], sv);
        }
    }
    __syncthreads();

    // ---- f2out matvec 2 + residual ----
    {
        float p[4] = {0.f, 0.f, 0.f, 0.f};
        const int hb = kq * 64;
        #pragma unroll 1
        for (int c = 0; c < 8; ++c) {
            const int h0 = hb + c * 8;
            float4 wq[8];
            #pragma unroll
            for (int j = 0; j < 8; ++j)
                wq[j] = LDG4(&fw2[(h0 + j) * Ff + fbase]);
            const float4 a0 = LDG4(&sv_s[h0]);
            const float4 a1 = LDG4(&sv_s[h0 + 4]);
            FMA4(p, a0.x, wq[0]); FMA4(p, a0.y, wq[1]);
            FMA4(p, a0.z, wq[2]); FMA4(p, a0.w, wq[3]);
            FMA4(p, a1.x, wq[4]); FMA4(p, a1.y, wq[5]);
            FMA4(p, a1.z, wq[6]); FMA4(p, a1.w, wq[7]);
        }
        #pragma unroll
        for (int j = 0; j < 4; ++j) {
            p[j] += __shfl_xor(p[j], 16);
            p[j] += __shfl_xor(p[j], 32);
        }
        if (kq == 0) {
            const float4 fb2q = LDG4(&fb2[fbase]);
            float4 xv = LDG4(&x[bn * Ff + fbase]);
            xv.x += p[0] + fb2q.x;
            xv.y += p[1] + fb2q.y;
            xv.z += p[2] + fb2q.z;
            xv.w += p[3] + fb2q.w;
            ST4(&x[bn * Ff + fbase], xv);
        }
    }
}

// ---------------------------------------------------------------------------
// k_head: disp/frac/rep, predictor MLP, masked mean, new_cell, new_pos
// ---------------------------------------------------------------------------
__global__ __launch_bounds__(128) void k_head(
    const float* __restrict__ x, const float* __restrict__ pos,
    const float* __restrict__ cell, const float* __restrict__ amask,
    const float* __restrict__ fdw, const float* __restrict__ fdb,
    const float* __restrict__ pw1, const float* __restrict__ pb1,
    const float* __restrict__ pw2, const float* __restrict__ pb2,
    float* __restrict__ out_pos, float* __restrict__ out_cell)
{
    const int b = blockIdx.x;
    const int n = threadIdx.x;

    __shared__ float sinv[9];
    __shared__ float scell[9];
    __shared__ float snc[9];
    __shared__ float sred[Nn][10];

    if (n == 0) {
        float c[9];
        #pragma unroll
        for (int i = 0; i < 9; ++i) { c[i] = cell[b * 9 + i]; scell[i] = c[i]; }
        float det = c[0] * (c[4] * c[8] - c[5] * c[7])
                  - c[1] * (c[3] * c[8] - c[5] * c[6])
                  + c[2] * (c[3] * c[7] - c[4] * c[6]);
        float id = 1.0f / det;
        sinv[0] = (c[4] * c[8] - c[5] * c[7]) * id;
        sinv[1] = (c[2] * c[7] - c[1] * c[8]) * id;
        sinv[2] = (c[1] * c[5] - c[2] * c[4]) * id;
        sinv[3] = (c[5] * c[6] - c[3] * c[8]) * id;
        sinv[4] = (c[0] * c[8] - c[2] * c[6]) * id;
        sinv[5] = (c[2] * c[3] - c[0] * c[5]) * id;
        sinv[6] = (c[3] * c[7] - c[4] * c[6]) * id;
        sinv[7] = (c[1] * c[6] - c[0] * c[7]) * id;
        sinv[8] = (c[0] * c[4] - c[1] * c[3]) * id;
    }
    __syncthreads();

    float xv0 = 0.f, xv1 = 0.f, xv2 = 0.f;
    const int row = (b * Nn + n) * Ff;
    for (int ff = 0; ff < Ff; ++ff) {
        float xr = x[row + ff];
        xv0 = fmaf(xr, fdw[ff * 3 + 0], xv0);
        xv1 = fmaf(xr, fdw[ff * 3 + 1], xv1);
        xv2 = fmaf(xr, fdw[ff * 3 + 2], xv2);
    }
    float fr[3];
    float dsp[3] = {xv0, xv1, xv2};
    const float p0 = pos[(b * Nn + n) * 3 + 0];
    const float p1 = pos[(b * Nn + n) * 3 + 1];
    const float p2 = pos[(b * Nn + n) * 3 + 2];
    #pragma unroll
    for (int j = 0; j < 3; ++j) {
        float z = 10.0f * (dsp[j] + fdb[j]);
        float s = 1.0f / (1.0f + expf(-z));
        float fx = p0 * sinv[0 * 3 + j] + p1 * sinv[1 * 3 + j] + p2 * sinv[2 * 3 + j] + s;
        fr[j] = fx - floorf(fx);
    }

    float rep[3];
    #pragma unroll
    for (int j = 0; j < 3; ++j)
        rep[j] = fr[0] * scell[0 * 3 + j] + fr[1] * scell[1 * 3 + j] + fr[2] * scell[2 * 3 + j];

    float a6[6];
    #pragma unroll
    for (int i = 0; i < 6; ++i) {
        float uv = rep[0] * pw1[0 * 6 + i] + rep[1] * pw1[1 * 6 + i]
                 + rep[2] * pw1[2 * 6 + i] + pb1[i];
        a6[i] = ssp_f(uv);
    }
    float h9[9];
    #pragma unroll
    for (int o = 0; o < 9; ++o) {
        float uv = pb2[o];
        #pragma unroll
        for (int i = 0; i < 6; ++i) uv = fmaf(a6[i], pw2[i * 9 + o], uv);
        h9[o] = uv;
    }

    const float m = amask[b * Nn + n];
    #pragma unroll
    for (int o = 0; o < 9; ++o) sred[n][o] = h9[o] * m;
    sred[n][9] = m;
    __syncthreads();

    for (int s = 64; s >= 1; s >>= 1) {
        if (n < s) {
            #pragma unroll
            for (int o = 0; o < 10; ++o) sred[n][o] += sred[n + s][o];
        }
        __syncthreads();
    }

    if (n < 9) {
        float na = sred[0][9];
        float yo = sred[0][n] / na;
        float scale = 3.0f * powf(na, 1.0f / 3.0f);
        int r = n / 3, c = n - r * 3;
        float v = scale * (((r == c) ? 1.0f : 0.0f) + yo);
        snc[n] = v;
        out_cell[b * 9 + n] = v;
    }
    __syncthreads();

    #pragma unroll
    for (int j = 0; j < 3; ++j) {
        float v = fr[0] * snc[0 * 3 + j] + fr[1] * snc[1 * 3 + j] + fr[2] * snc[2 * 3 + j];
        out_pos[(b * Nn + n) * 3 + j] = v;
    }
}

// ---------------------------------------------------------------------------
extern "C" void kernel_launch(void* const* d_in, const int* in_sizes, int n_in,
                              void* d_out, int out_size, void* d_ws, size_t ws_size,
                              hipStream_t stream)
{
    const float* positions     = (const float*)d_in[0];
    const float* cell          = (const float*)d_in[1];
    const int*   atomic_nums   = (const int*)  d_in[2];
    const int*   neighbors     = (const int*)  d_in[3];
    const float* neighbor_mask = (const float*)d_in[4];
    const float* atom_mask     = (const float*)d_in[5];
    const float* embedding     = (const float*)d_in[6];
    const float* filt_w1       = (const float*)d_in[7];
    const float* filt_b1       = (const float*)d_in[8];
    const float* filt_w2       = (const float*)d_in[9];
    const float* filt_b2       = (const float*)d_in[10];
    const float* in2f_w        = (const float*)d_in[11];
    const float* f2out_w1      = (const float*)d_in[12];
    const float* f2out_b1      = (const float*)d_in[13];
    const float* f2out_w2      = (const float*)d_in[14];
    const float* f2out_b2      = (const float*)d_in[15];
    const float* fd_w          = (const float*)d_in[16];
    const float* fd_b          = (const float*)d_in[17];
    const float* pred_w1       = (const float*)d_in[18];
    const float* pred_b1       = (const float*)d_in[19];
    const float* pred_w2       = (const float*)d_in[20];
    const float* pred_b2       = (const float*)d_in[21];

    float* ws   = (float*)d_ws;
    float* x    = ws;
    float* y    = x + Bb * Nn * Ff;
    float* fexp = y + Bb * Nn * Ff;
    float* fcut = fexp + Bb * Nn * Kk * Gg;

    float* out_pos  = (float*)d_out;
    float* out_cell = out_pos + Bb * Nn * 3;

    const int BN = Bb * Nn;

    k_setup<<<BN, 256, 0, stream>>>(positions, atomic_nums, neighbors,
                                    neighbor_mask, embedding, x, fexp, fcut);

    for (int t = 0; t < Tt; ++t) {
        k_y4<<<BN / 4, 256, 0, stream>>>(x, in2f_w + (size_t)t * Ff * Ff, y);
        k_agg4<<<BN, 256, 0, stream>>>(fexp, fcut, neighbors, y,
                                       filt_w1 + (size_t)t * Gg * Ff,
                                       filt_b1 + (size_t)t * Ff,
                                       filt_w2 + (size_t)t * Ff * Ff,
                                       filt_b2 + (size_t)t * Ff,
                                       f2out_w1 + (size_t)t * Ff * Ff,
                                       f2out_b1 + (size_t)t * Ff,
                                       f2out_w2 + (size_t)t * Ff * Ff,
                                       f2out_b2 + (size_t)t * Ff,
                                       x);
    }

    k_head<<<Bb, 128, 0, stream>>>(x, positions, cell, atom_mask,
                                   fd_w, fd_b, pred_w1, pred_b1, pred_w2, pred_b2,
                                   out_pos, out_cell);
}

// Round 9
// 1666.984 us; speedup vs baseline: 2.0664x; 2.0664x over previous
//
#include <hip/hip_runtime.h>
#include <math.h>

#define Bb 32
#define Nn 128
#define Kk 48
#define Ff 256
#define Gg 50
#define Tt 3

__device__ __forceinline__ float ssp_f(float v) {
    return fmaxf(v, 0.f) + log1pf(expf(-fabsf(v))) - 0.69314718055994530942f;
}

#define LDG4(p) (*reinterpret_cast<const float4*>(p))
#define ST4(p, v) (*reinterpret_cast<float4*>(p) = (v))

// dst[4] += s * vv.{x,y,z,w}   (param must NOT be named like a member!)
#define FMA4(dst, s, vv)                      \
    dst[0] = fmaf((s), (vv).x, dst[0]);       \
    dst[1] = fmaf((s), (vv).y, dst[1]);       \
    dst[2] = fmaf((s), (vv).z, dst[2]);       \
    dst[3] = fmaf((s), (vv).w, dst[3]);

// ---------------------------------------------------------------------------
// k_setup: x = embedding[z]; d, fexp, fcut per (b,n,k)
// ---------------------------------------------------------------------------
__global__ __launch_bounds__(256) void k_setup(
    const float* __restrict__ pos, const int* __restrict__ zz,
    const int* __restrict__ nbr, const float* __restrict__ nmask,
    const float* __restrict__ emb,
    float* __restrict__ x, float* __restrict__ fexp, float* __restrict__ fcut)
{
    const int bn = blockIdx.x;
    const int b  = bn >> 7;
    const int t  = threadIdx.x;
    __shared__ float sd[Kk];

    x[bn * Ff + t] = emb[zz[bn] * Ff + t];

    if (t < Kk) {
        int j = nbr[bn * Kk + t];
        float px = pos[bn * 3 + 0], py = pos[bn * 3 + 1], pz = pos[bn * 3 + 2];
        int rj = (b * Nn + j) * 3;
        float dx = pos[rj + 0] - px;
        float dy = pos[rj + 1] - py;
        float dz = pos[rj + 2] - pz;
        float d = sqrtf(fmaf(dx, dx, fmaf(dy, dy, dz * dz)) + 1e-8f);
        sd[t] = d;
        float fc = 0.5f * (cosf(3.14159265358979323846f * d / 5.0f) + 1.0f);
        fc = (d < 5.0f) ? fc : 0.0f;
        fcut[bn * Kk + t] = fc * nmask[bn * Kk + t];
    }
    __syncthreads();

    const float step = 5.0f / 49.0f;
    const float coeff = -0.5f / (step * step);
    for (int i = t; i < Kk * Gg; i += 256) {
        int k = i / Gg, g = i - k * Gg;
        float dd = sd[k] - step * (float)g;
        fexp[bn * (Kk * Gg) + i] = expf(coeff * dd * dd);
    }
}

// ---------------------------------------------------------------------------
// k_y4: y = x @ in2f_w[t] for 4 atoms per block (w read once per 4 atoms)
// ---------------------------------------------------------------------------
__global__ __launch_bounds__(256) void k_y4(
    const float* __restrict__ x, const float* __restrict__ w,
    float* __restrict__ y)
{
    const int bn0 = blockIdx.x * 4;
    const int tid = threadIdx.x;
    const int tx  = tid & 63;
    const int ty  = tid >> 6;
    const int f4  = tx * 4;

    __shared__ __align__(16) float sx[4][Ff];        // 4 KB
    __shared__ __align__(16) float p4s[4][4][Ff];    // 16 KB [ty][atom][f]

    #pragma unroll
    for (int a = 0; a < 4; ++a)
        sx[a][tid] = x[(bn0 + a) * Ff + tid];
    __syncthreads();

    float p0[4] = {0.f, 0.f, 0.f, 0.f};
    float p1[4] = {0.f, 0.f, 0.f, 0.f};
    float p2[4] = {0.f, 0.f, 0.f, 0.f};
    float p3[4] = {0.f, 0.f, 0.f, 0.f};

    #pragma unroll 1
    for (int hh = 0; hh < 64; hh += 8) {
        const int h0 = ty * 64 + hh;
        float4 wq[8];
        #pragma unroll
        for (int j = 0; j < 8; ++j)
            wq[j] = LDG4(&w[(h0 + j) * Ff + f4]);

        {
            const float4 a0 = LDG4(&sx[0][h0]);
            const float4 a1 = LDG4(&sx[0][h0 + 4]);
            FMA4(p0, a0.x, wq[0]); FMA4(p0, a0.y, wq[1]);
            FMA4(p0, a0.z, wq[2]); FMA4(p0, a0.w, wq[3]);
            FMA4(p0, a1.x, wq[4]); FMA4(p0, a1.y, wq[5]);
            FMA4(p0, a1.z, wq[6]); FMA4(p0, a1.w, wq[7]);
        }
        {
            const float4 a0 = LDG4(&sx[1][h0]);
            const float4 a1 = LDG4(&sx[1][h0 + 4]);
            FMA4(p1, a0.x, wq[0]); FMA4(p1, a0.y, wq[1]);
            FMA4(p1, a0.z, wq[2]); FMA4(p1, a0.w, wq[3]);
            FMA4(p1, a1.x, wq[4]); FMA4(p1, a1.y, wq[5]);
            FMA4(p1, a1.z, wq[6]); FMA4(p1, a1.w, wq[7]);
        }
        {
            const float4 a0 = LDG4(&sx[2][h0]);
            const float4 a1 = LDG4(&sx[2][h0 + 4]);
            FMA4(p2, a0.x, wq[0]); FMA4(p2, a0.y, wq[1]);
            FMA4(p2, a0.z, wq[2]); FMA4(p2, a0.w, wq[3]);
            FMA4(p2, a1.x, wq[4]); FMA4(p2, a1.y, wq[5]);
            FMA4(p2, a1.z, wq[6]); FMA4(p2, a1.w, wq[7]);
        }
        {
            const float4 a0 = LDG4(&sx[3][h0]);
            const float4 a1 = LDG4(&sx[3][h0 + 4]);
            FMA4(p3, a0.x, wq[0]); FMA4(p3, a0.y, wq[1]);
            FMA4(p3, a0.z, wq[2]); FMA4(p3, a0.w, wq[3]);
            FMA4(p3, a1.x, wq[4]); FMA4(p3, a1.y, wq[5]);
            FMA4(p3, a1.z, wq[6]); FMA4(p3, a1.w, wq[7]);
        }
    }
    ST4(&p4s[ty][0][f4], make_float4(p0[0], p0[1], p0[2], p0[3]));
    ST4(&p4s[ty][1][f4], make_float4(p1[0], p1[1], p1[2], p1[3]));
    ST4(&p4s[ty][2][f4], make_float4(p2[0], p2[1], p2[2], p2[3]));
    ST4(&p4s[ty][3][f4], make_float4(p3[0], p3[1], p3[2], p3[3]));
    __syncthreads();

    #pragma unroll
    for (int a = 0; a < 4; ++a)
        y[(bn0 + a) * Ff + tid] = p4s[0][a][tid] + p4s[1][a][tid]
                                + p4s[2][a][tid] + p4s[3][a][tid];
}

// ---------------------------------------------------------------------------
// k_agg5: one atom per block, K in 2 passes of 24 rows -> 37.4 KB LDS
// (4 blocks/CU). Waves split F; lanes: kq = lane>>4, fq = lane&15.
// PLAIN __launch_bounds__(256): no min-waves arg — rounds 7/8 proved the
// compiler responds to it by slashing VGPRs below the live-set and spilling
// (64 and 84 VGPR, 0.16-1.7 GB scratch). Natural allocation (~100) is
// spill-free and still allows 4 waves/SIMD.
// ---------------------------------------------------------------------------
__global__ __launch_bounds__(256) void k_agg5(
    const float* __restrict__ fexp, const float* __restrict__ fcut,
    const int* __restrict__ nbr, const float* __restrict__ y,
    const float* __restrict__ w1, const float* __restrict__ b1,
    const float* __restrict__ w2, const float* __restrict__ b2,
    const float* __restrict__ fw1, const float* __restrict__ fb1,
    const float* __restrict__ fw2, const float* __restrict__ fb2,
    float* __restrict__ x)
{
    const int bn    = blockIdx.x;
    const int bbase = (bn >> 7) << 7;       // b * 128
    const int tid   = threadIdx.x;
    const int w     = tid >> 6;
    const int lane  = tid & 63;
    const int kq    = lane >> 4;            // 0..3
    const int fq    = lane & 15;            // 0..15
    const int fbase = w * 64 + fq * 4;
    const int lb    = kq * 6;               // local sH row base (per pass)

    __shared__ __align__(16) float sH[24][260];   // 24960 B (pass-local H)
    __shared__ __align__(16) float sfe[Kk][52];   // 9984 B
    __shared__ __align__(16) float agg_s[Ff];     // 1 KB
    __shared__ __align__(16) float sv_s[Ff];      // 1 KB
    __shared__ float scut[Kk];
    __shared__ int   snbr[Kk];

    // ---- coop loads ----
    for (int idx = tid; idx < Kk * Gg; idx += 256) {
        int r = idx / Gg, g = idx - r * Gg;
        sfe[r][g] = fexp[bn * (Kk * Gg) + idx];
    }
    if (tid < Kk) {
        scut[tid] = fcut[bn * Kk + tid];
        snbr[tid] = nbr[bn * Kk + tid];
    }
    __syncthreads();

    const float4 b1q = LDG4(&b1[fbase]);
    const float4 b2q = LDG4(&b2[fbase]);
    float aggp[4] = {0.f, 0.f, 0.f, 0.f};

    #pragma unroll 1
    for (int pass = 0; pass < 2; ++pass) {
        const int kb = pass * 24 + kq * 6;  // this thread's global k start

        // ---- filter layer 1: 6 rows ----
        float h1[6][4];
        #pragma unroll
        for (int rr = 0; rr < 6; ++rr) {
            h1[rr][0] = b1q.x; h1[rr][1] = b1q.y;
            h1[rr][2] = b1q.z; h1[rr][3] = b1q.w;
        }
        #pragma unroll 1
        for (int c = 0; c < 6; ++c) {
            const int g0 = c * 8;
            float4 wq[8];
            #pragma unroll
            for (int j = 0; j < 8; ++j)
                wq[j] = LDG4(&w1[(g0 + j) * Ff + fbase]);
            #pragma unroll
            for (int rr = 0; rr < 6; ++rr) {
                const float4 fe0 = LDG4(&sfe[kb + rr][g0]);
                const float4 fe1 = LDG4(&sfe[kb + rr][g0 + 4]);
                FMA4(h1[rr], fe0.x, wq[0]); FMA4(h1[rr], fe0.y, wq[1]);
                FMA4(h1[rr], fe0.z, wq[2]); FMA4(h1[rr], fe0.w, wq[3]);
                FMA4(h1[rr], fe1.x, wq[4]); FMA4(h1[rr], fe1.y, wq[5]);
                FMA4(h1[rr], fe1.z, wq[6]); FMA4(h1[rr], fe1.w, wq[7]);
            }
        }
        {
            const float4 wt0 = LDG4(&w1[48 * Ff + fbase]);
            const float4 wt1 = LDG4(&w1[49 * Ff + fbase]);
            #pragma unroll
            for (int rr = 0; rr < 6; ++rr) {
                const float fa = sfe[kb + rr][48];
                const float fb = sfe[kb + rr][49];
                FMA4(h1[rr], fa, wt0);
                FMA4(h1[rr], fb, wt1);
                float4 hv;
                hv.x = ssp_f(h1[rr][0]); hv.y = ssp_f(h1[rr][1]);
                hv.z = ssp_f(h1[rr][2]); hv.w = ssp_f(h1[rr][3]);
                ST4(&sH[lb + rr][fbase], hv);
            }
        }
        __syncthreads();

        // ---- filter layer 2: 6 rows x full h ----
        float acc[6][4];
        #pragma unroll
        for (int rr = 0; rr < 6; ++rr) {
            acc[rr][0] = 0.f; acc[rr][1] = 0.f;
            acc[rr][2] = 0.f; acc[rr][3] = 0.f;
        }
        #pragma unroll 1
        for (int c = 0; c < 32; ++c) {
            const int h0 = c * 8;
            float4 wq[8];
            #pragma unroll
            for (int j = 0; j < 8; ++j)
                wq[j] = LDG4(&w2[(h0 + j) * Ff + fbase]);
            #pragma unroll
            for (int rr = 0; rr < 6; ++rr) {
                const float4 s0 = LDG4(&sH[lb + rr][h0]);
                const float4 s1 = LDG4(&sH[lb + rr][h0 + 4]);
                FMA4(acc[rr], s0.x, wq[0]); FMA4(acc[rr], s0.y, wq[1]);
                FMA4(acc[rr], s0.z, wq[2]); FMA4(acc[rr], s0.w, wq[3]);
                FMA4(acc[rr], s1.x, wq[4]); FMA4(acc[rr], s1.y, wq[5]);
                FMA4(acc[rr], s1.z, wq[6]); FMA4(acc[rr], s1.w, wq[7]);
            }
        }

        // ---- cutoff + neighbor y gather (this pass's 6 rows) ----
        #pragma unroll
        for (int rr = 0; rr < 6; ++rr) {
            const float ct = scut[kb + rr];
            const int   nb = snbr[kb + rr];
            const float4 yv = LDG4(&y[(bbase + nb) * Ff + fbase]);
            aggp[0] = fmaf((acc[rr][0] + b2q.x) * ct, yv.x, aggp[0]);
            aggp[1] = fmaf((acc[rr][1] + b2q.y) * ct, yv.y, aggp[1]);
            aggp[2] = fmaf((acc[rr][2] + b2q.z) * ct, yv.z, aggp[2]);
            aggp[3] = fmaf((acc[rr][3] + b2q.w) * ct, yv.w, aggp[3]);
        }
        __syncthreads();   // before next pass overwrites sH
    }

    // in-register reduce across kq (lane bits 4,5)
    #pragma unroll
    for (int j = 0; j < 4; ++j) {
        aggp[j] += __shfl_xor(aggp[j], 16);
        aggp[j] += __shfl_xor(aggp[j], 32);
    }
    if (kq == 0)
        ST4(&agg_s[fbase], make_float4(aggp[0], aggp[1], aggp[2], aggp[3]));
    __syncthreads();

    // ---- f2out matvec 1: kq reinterpreted as h-quarter ----
    {
        float p[4] = {0.f, 0.f, 0.f, 0.f};
        const int hb = kq * 64;
        #pragma unroll 1
        for (int c = 0; c < 8; ++c) {
            const int h0 = hb + c * 8;
            float4 wq[8];
            #pragma unroll
            for (int j = 0; j < 8; ++j)
                wq[j] = LDG4(&fw1[(h0 + j) * Ff + fbase]);
            const float4 a0 = LDG4(&agg_s[h0]);
            const float4 a1 = LDG4(&agg_s[h0 + 4]);
            FMA4(p, a0.x, wq[0]); FMA4(p, a0.y, wq[1]);
            FMA4(p, a0.z, wq[2]); FMA4(p, a0.w, wq[3]);
            FMA4(p, a1.x, wq[4]); FMA4(p, a1.y, wq[5]);
            FMA4(p, a1.z, wq[6]); FMA4(p, a1.w, wq[7]);
        }
        #pragma unroll
        for (int j = 0; j < 4; ++j) {
            p[j] += __shfl_xor(p[j], 16);
            p[j] += __shfl_xor(p[j], 32);
        }
        if (kq == 0) {
            const float4 fb1q = LDG4(&fb1[fbase]);
            float4 sv;
            sv.x = ssp_f(p[0] + fb1q.x); sv.y = ssp_f(p[1] + fb1q.y);
            sv.z = ssp_f(p[2] + fb1q.z); sv.w = ssp_f(p[3] + fb1q.w);
            ST4(&sv_s[fbase], sv);
        }
    }
    __syncthreads();

    // ---- f2out matvec 2 + residual ----
    {
        float p[4] = {0.f, 0.f, 0.f, 0.f};
        const int hb = kq * 64;
        #pragma unroll 1
        for (int c = 0; c < 8; ++c) {
            const int h0 = hb + c * 8;
            float4 wq[8];
            #pragma unroll
            for (int j = 0; j < 8; ++j)
                wq[j] = LDG4(&fw2[(h0 + j) * Ff + fbase]);
            const float4 a0 = LDG4(&sv_s[h0]);
            const float4 a1 = LDG4(&sv_s[h0 + 4]);
            FMA4(p, a0.x, wq[0]); FMA4(p, a0.y, wq[1]);
            FMA4(p, a0.z, wq[2]); FMA4(p, a0.w, wq[3]);
            FMA4(p, a1.x, wq[4]); FMA4(p, a1.y, wq[5]);
            FMA4(p, a1.z, wq[6]); FMA4(p, a1.w, wq[7]);
        }
        #pragma unroll
        for (int j = 0; j < 4; ++j) {
            p[j] += __shfl_xor(p[j], 16);
            p[j] += __shfl_xor(p[j], 32);
        }
        if (kq == 0) {
            const float4 fb2q = LDG4(&fb2[fbase]);
            float4 xv = LDG4(&x[bn * Ff + fbase]);
            xv.x += p[0] + fb2q.x;
            xv.y += p[1] + fb2q.y;
            xv.z += p[2] + fb2q.z;
            xv.w += p[3] + fb2q.w;
            ST4(&x[bn * Ff + fbase], xv);
        }
    }
}

// ---------------------------------------------------------------------------
// k_head: disp/frac/rep, predictor MLP, masked mean, new_cell, new_pos
// ---------------------------------------------------------------------------
__global__ __launch_bounds__(128) void k_head(
    const float* __restrict__ x, const float* __restrict__ pos,
    const float* __restrict__ cell, const float* __restrict__ amask,
    const float* __restrict__ fdw, const float* __restrict__ fdb,
    const float* __restrict__ pw1, const float* __restrict__ pb1,
    const float* __restrict__ pw2, const float* __restrict__ pb2,
    float* __restrict__ out_pos, float* __restrict__ out_cell)
{
    const int b = blockIdx.x;
    const int n = threadIdx.x;

    __shared__ float sinv[9];
    __shared__ float scell[9];
    __shared__ float snc[9];
    __shared__ float sred[Nn][10];

    if (n == 0) {
        float c[9];
        #pragma unroll
        for (int i = 0; i < 9; ++i) { c[i] = cell[b * 9 + i]; scell[i] = c[i]; }
        float det = c[0] * (c[4] * c[8] - c[5] * c[7])
                  - c[1] * (c[3] * c[8] - c[5] * c[6])
                  + c[2] * (c[3] * c[7] - c[4] * c[6]);
        float id = 1.0f / det;
        sinv[0] = (c[4] * c[8] - c[5] * c[7]) * id;
        sinv[1] = (c[2] * c[7] - c[1] * c[8]) * id;
        sinv[2] = (c[1] * c[5] - c[2] * c[4]) * id;
        sinv[3] = (c[5] * c[6] - c[3] * c[8]) * id;
        sinv[4] = (c[0] * c[8] - c[2] * c[6]) * id;
        sinv[5] = (c[2] * c[3] - c[0] * c[5]) * id;
        sinv[6] = (c[3] * c[7] - c[4] * c[6]) * id;
        sinv[7] = (c[1] * c[6] - c[0] * c[7]) * id;
        sinv[8] = (c[0] * c[4] - c[1] * c[3]) * id;
    }
    __syncthreads();

    float xv0 = 0.f, xv1 = 0.f, xv2 = 0.f;
    const int row = (b * Nn + n) * Ff;
    for (int ff = 0; ff < Ff; ++ff) {
        float xr = x[row + ff];
        xv0 = fmaf(xr, fdw[ff * 3 + 0], xv0);
        xv1 = fmaf(xr, fdw[ff * 3 + 1], xv1);
        xv2 = fmaf(xr, fdw[ff * 3 + 2], xv2);
    }
    float fr[3];
    float dsp[3] = {xv0, xv1, xv2};
    const float p0 = pos[(b * Nn + n) * 3 + 0];
    const float p1 = pos[(b * Nn + n) * 3 + 1];
    const float p2 = pos[(b * Nn + n) * 3 + 2];
    #pragma unroll
    for (int j = 0; j < 3; ++j) {
        float z = 10.0f * (dsp[j] + fdb[j]);
        float s = 1.0f / (1.0f + expf(-z));
        float fx = p0 * sinv[0 * 3 + j] + p1 * sinv[1 * 3 + j] + p2 * sinv[2 * 3 + j] + s;
        fr[j] = fx - floorf(fx);
    }

    float rep[3];
    #pragma unroll
    for (int j = 0; j < 3; ++j)
        rep[j] = fr[0] * scell[0 * 3 + j] + fr[1] * scell[1 * 3 + j] + fr[2] * scell[2 * 3 + j];

    float a6[6];
    #pragma unroll
    for (int i = 0; i < 6; ++i) {
        float uv = rep[0] * pw1[0 * 6 + i] + rep[1] * pw1[1 * 6 + i]
                 + rep[2] * pw1[2 * 6 + i] + pb1[i];
        a6[i] = ssp_f(uv);
    }
    float h9[9];
    #pragma unroll
    for (int o = 0; o < 9; ++o) {
        float uv = pb2[o];
        #pragma unroll
        for (int i = 0; i < 6; ++i) uv = fmaf(a6[i], pw2[i * 9 + o], uv);
        h9[o] = uv;
    }

    const float m = amask[b * Nn + n];
    #pragma unroll
    for (int o = 0; o < 9; ++o) sred[n][o] = h9[o] * m;
    sred[n][9] = m;
    __syncthreads();

    for (int s = 64; s >= 1; s >>= 1) {
        if (n < s) {
            #pragma unroll
            for (int o = 0; o < 10; ++o) sred[n][o] += sred[n + s][o];
        }
        __syncthreads();
    }

    if (n < 9) {
        float na = sred[0][9];
        float yo = sred[0][n] / na;
        float scale = 3.0f * powf(na, 1.0f / 3.0f);
        int r = n / 3, c = n - r * 3;
        float v = scale * (((r == c) ? 1.0f : 0.0f) + yo);
        snc[n] = v;
        out_cell[b * 9 + n] = v;
    }
    __syncthreads();

    #pragma unroll
    for (int j = 0; j < 3; ++j) {
        float v = fr[0] * snc[0 * 3 + j] + fr[1] * snc[1 * 3 + j] + fr[2] * snc[2 * 3 + j];
        out_pos[(b * Nn + n) * 3 + j] = v;
    }
}

// ---------------------------------------------------------------------------
extern "C" void kernel_launch(void* const* d_in, const int* in_sizes, int n_in,
                              void* d_out, int out_size, void* d_ws, size_t ws_size,
                              hipStream_t stream)
{
    const float* positions     = (const float*)d_in[0];
    const float* cell          = (const float*)d_in[1];
    const int*   atomic_nums   = (const int*)  d_in[2];
    const int*   neighbors     = (const int*)  d_in[3];
    const float* neighbor_mask = (const float*)d_in[4];
    const float* atom_mask     = (const float*)d_in[5];
    const float* embedding     = (const float*)d_in[6];
    const float* filt_w1       = (const float*)d_in[7];
    const float* filt_b1       = (const float*)d_in[8];
    const float* filt_w2       = (const float*)d_in[9];
    const float* filt_b2       = (const float*)d_in[10];
    const float* in2f_w        = (const float*)d_in[11];
    const float* f2out_w1      = (const float*)d_in[12];
    const float* f2out_b1      = (const float*)d_in[13];
    const float* f2out_w2      = (const float*)d_in[14];
    const float* f2out_b2      = (const float*)d_in[15];
    const float* fd_w          = (const float*)d_in[16];
    const float* fd_b          = (const float*)d_in[17];
    const float* pred_w1       = (const float*)d_in[18];
    const float* pred_b1       = (const float*)d_in[19];
    const float* pred_w2       = (const float*)d_in[20];
    const float* pred_b2       = (const float*)d_in[21];

    float* ws   = (float*)d_ws;
    float* x    = ws;
    float* y    = x + Bb * Nn * Ff;
    float* fexp = y + Bb * Nn * Ff;
    float* fcut = fexp + Bb * Nn * Kk * Gg;

    float* out_pos  = (float*)d_out;
    float* out_cell = out_pos + Bb * Nn * 3;

    const int BN = Bb * Nn;

    k_setup<<<BN, 256, 0, stream>>>(positions, atomic_nums, neighbors,
                                    neighbor_mask, embedding, x, fexp, fcut);

    for (int t = 0; t < Tt; ++t) {
        k_y4<<<BN / 4, 256, 0, stream>>>(x, in2f_w + (size_t)t * Ff * Ff, y);
        k_agg5<<<BN, 256, 0, stream>>>(fexp, fcut, neighbors, y,
                                       filt_w1 + (size_t)t * Gg * Ff,
                                       filt_b1 + (size_t)t * Ff,
                                       filt_w2 + (size_t)t * Ff * Ff,
                                       filt_b2 + (size_t)t * Ff,
                                       f2out_w1 + (size_t)t * Ff * Ff,
                                       f2out_b1 + (size_t)t * Ff,
                                       f2out_w2 + (size_t)t * Ff * Ff,
                                       f2out_b2 + (size_t)t * Ff,
                                       x);
    }

    k_head<<<Bb, 128, 0, stream>>>(x, positions, cell, atom_mask,
                                   fd_w, fd_b, pred_w1, pred_b1, pred_w2, pred_b2,
                                   out_pos, out_cell);
}

// Round 10
// 1565.995 us; speedup vs baseline: 2.1996x; 1.0645x over previous
//
#include <hip/hip_runtime.h>
#include <math.h>

#define Bb 32
#define Nn 128
#define Kk 48
#define Ff 256
#define Gg 50
#define Tt 3

typedef __attribute__((ext_vector_type(8))) short bf16x8;
typedef __attribute__((ext_vector_type(4))) float f32x4;

#define MFMA_B16(a, b, c) __builtin_amdgcn_mfma_f32_16x16x32_bf16((a), (b), (c), 0, 0, 0)

__device__ __forceinline__ float ssp_f(float v) {
    return fmaxf(v, 0.f) + log1pf(expf(-fabsf(v))) - 0.69314718055994530942f;
}

// f32 -> bf16 (RNE) and back, via bit ops (no type-system surprises)
__device__ __forceinline__ unsigned short f2bf(float x) {
    union { float f; unsigned int u; } v; v.f = x;
    unsigned int r = v.u + 0x7FFFu + ((v.u >> 16) & 1u);
    return (unsigned short)(r >> 16);
}
__device__ __forceinline__ float bf2f(unsigned short h) {
    union { unsigned int u; float f; } v; v.u = ((unsigned int)h) << 16;
    return v.f;
}

#define LDG4(p) (*reinterpret_cast<const float4*>(p))
#define ST4(p, v) (*reinterpret_cast<float4*>(p) = (v))

#define FMA4(dst, s, vv)                      \
    dst[0] = fmaf((s), (vv).x, dst[0]);       \
    dst[1] = fmaf((s), (vv).y, dst[1]);       \
    dst[2] = fmaf((s), (vv).z, dst[2]);       \
    dst[3] = fmaf((s), (vv).w, dst[3]);

// ---------------------------------------------------------------------------
// k_setup: x = embedding[z]; d (raw distance), fcut per (b,n,k)
// ---------------------------------------------------------------------------
__global__ __launch_bounds__(256) void k_setup(
    const float* __restrict__ pos, const int* __restrict__ zz,
    const int* __restrict__ nbr, const float* __restrict__ nmask,
    const float* __restrict__ emb,
    float* __restrict__ x, float* __restrict__ sd_g, float* __restrict__ fcut)
{
    const int bn = blockIdx.x;
    const int b  = bn >> 7;
    const int t  = threadIdx.x;

    x[bn * Ff + t] = emb[zz[bn] * Ff + t];

    if (t < Kk) {
        int j = nbr[bn * Kk + t];
        float px = pos[bn * 3 + 0], py = pos[bn * 3 + 1], pz = pos[bn * 3 + 2];
        int rj = (b * Nn + j) * 3;
        float dx = pos[rj + 0] - px;
        float dy = pos[rj + 1] - py;
        float dz = pos[rj + 2] - pz;
        float d = sqrtf(fmaf(dx, dx, fmaf(dy, dy, dz * dz)) + 1e-8f);
        sd_g[bn * Kk + t] = d;
        float fc = 0.5f * (cosf(3.14159265358979323846f * d / 5.0f) + 1.0f);
        fc = (d < 5.0f) ? fc : 0.0f;
        fcut[bn * Kk + t] = fc * nmask[bn * Kk + t];
    }
}

// ---------------------------------------------------------------------------
// k_wsplit: per t, split filt_w2 (f32 [K=256][N=256]) into hi/lo bf16,
// TRANSPOSED to [n][k] so MFMA B-fragments are contiguous 16B loads.
// grid: 3*256 blocks (t,n); 256 threads (k)
// ---------------------------------------------------------------------------
__global__ __launch_bounds__(256) void k_wsplit(
    const float* __restrict__ w2all,
    unsigned short* __restrict__ whT, unsigned short* __restrict__ wlT)
{
    const int blk = blockIdx.x;
    const int t = blk >> 8;
    const int n = blk & 255;
    const int k = threadIdx.x;
    float v = w2all[(size_t)t * Ff * Ff + (size_t)k * Ff + n];
    unsigned short hi = f2bf(v);
    unsigned short lo = f2bf(v - bf2f(hi));
    whT[(size_t)t * Ff * Ff + (size_t)n * Ff + k] = hi;
    wlT[(size_t)t * Ff * Ff + (size_t)n * Ff + k] = lo;
}

// ---------------------------------------------------------------------------
// k_y4: y = x @ in2f_w[t] for 4 atoms per block
// ---------------------------------------------------------------------------
__global__ __launch_bounds__(256) void k_y4(
    const float* __restrict__ x, const float* __restrict__ w,
    float* __restrict__ y)
{
    const int bn0 = blockIdx.x * 4;
    const int tid = threadIdx.x;
    const int tx  = tid & 63;
    const int ty  = tid >> 6;
    const int f4  = tx * 4;

    __shared__ __align__(16) float sx[4][Ff];
    __shared__ __align__(16) float p4s[4][4][Ff];

    #pragma unroll
    for (int a = 0; a < 4; ++a)
        sx[a][tid] = x[(bn0 + a) * Ff + tid];
    __syncthreads();

    float p0[4] = {0.f, 0.f, 0.f, 0.f};
    float p1[4] = {0.f, 0.f, 0.f, 0.f};
    float p2[4] = {0.f, 0.f, 0.f, 0.f};
    float p3[4] = {0.f, 0.f, 0.f, 0.f};

    #pragma unroll 1
    for (int hh = 0; hh < 64; hh += 8) {
        const int h0 = ty * 64 + hh;
        float4 wq[8];
        #pragma unroll
        for (int j = 0; j < 8; ++j)
            wq[j] = LDG4(&w[(h0 + j) * Ff + f4]);
        {
            const float4 a0 = LDG4(&sx[0][h0]);
            const float4 a1 = LDG4(&sx[0][h0 + 4]);
            FMA4(p0, a0.x, wq[0]); FMA4(p0, a0.y, wq[1]);
            FMA4(p0, a0.z, wq[2]); FMA4(p0, a0.w, wq[3]);
            FMA4(p0, a1.x, wq[4]); FMA4(p0, a1.y, wq[5]);
            FMA4(p0, a1.z, wq[6]); FMA4(p0, a1.w, wq[7]);
        }
        {
            const float4 a0 = LDG4(&sx[1][h0]);
            const float4 a1 = LDG4(&sx[1][h0 + 4]);
            FMA4(p1, a0.x, wq[0]); FMA4(p1, a0.y, wq[1]);
            FMA4(p1, a0.z, wq[2]); FMA4(p1, a0.w, wq[3]);
            FMA4(p1, a1.x, wq[4]); FMA4(p1, a1.y, wq[5]);
            FMA4(p1, a1.z, wq[6]); FMA4(p1, a1.w, wq[7]);
        }
        {
            const float4 a0 = LDG4(&sx[2][h0]);
            const float4 a1 = LDG4(&sx[2][h0 + 4]);
            FMA4(p2, a0.x, wq[0]); FMA4(p2, a0.y, wq[1]);
            FMA4(p2, a0.z, wq[2]); FMA4(p2, a0.w, wq[3]);
            FMA4(p2, a1.x, wq[4]); FMA4(p2, a1.y, wq[5]);
            FMA4(p2, a1.z, wq[6]); FMA4(p2, a1.w, wq[7]);
        }
        {
            const float4 a0 = LDG4(&sx[3][h0]);
            const float4 a1 = LDG4(&sx[3][h0 + 4]);
            FMA4(p3, a0.x, wq[0]); FMA4(p3, a0.y, wq[1]);
            FMA4(p3, a0.z, wq[2]); FMA4(p3, a0.w, wq[3]);
            FMA4(p3, a1.x, wq[4]); FMA4(p3, a1.y, wq[5]);
            FMA4(p3, a1.z, wq[6]); FMA4(p3, a1.w, wq[7]);
        }
    }
    ST4(&p4s[ty][0][f4], make_float4(p0[0], p0[1], p0[2], p0[3]));
    ST4(&p4s[ty][1][f4], make_float4(p1[0], p1[1], p1[2], p1[3]));
    ST4(&p4s[ty][2][f4], make_float4(p2[0], p2[1], p2[2], p2[3]));
    ST4(&p4s[ty][3][f4], make_float4(p3[0], p3[1], p3[2], p3[3]));
    __syncthreads();

    #pragma unroll
    for (int a = 0; a < 4; ++a)
        y[(bn0 + a) * Ff + tid] = p4s[0][a][tid] + p4s[1][a][tid]
                                + p4s[2][a][tid] + p4s[3][a][tid];
}

// ---------------------------------------------------------------------------
// k_aggm: one atom per block.
//  layer 1 (VALU f32): H = ssp(fexp@w1+b1), stored to LDS as SPLIT bf16 (hi/lo)
//  layer 2 (MFMA):     W = H@w2+b2 via 3-product split-bf16 16x16x32 MFMA
//  consume:            agg[f] = sum_k (W+b2)*cut[k]*y[nbr[k]][f]
//  f2out (VALU f32):   x += ssp(agg@fw1+fb1)@fw2+fb2
// MFMA fragment maps (cdna4_isa/m89): A row=lane&15,k=(lane>>4)*8+i;
// B col=lane&15 (whT pre-transposed so k contiguous); D col=lane&15,
// row=(lane>>4)*4+reg.
// ---------------------------------------------------------------------------
__global__ __launch_bounds__(256) void k_aggm(
    const float* __restrict__ sd, const float* __restrict__ fcut,
    const int* __restrict__ nbr, const float* __restrict__ y,
    const float* __restrict__ w1, const float* __restrict__ b1,
    const unsigned short* __restrict__ whT, const unsigned short* __restrict__ wlT,
    const float* __restrict__ b2,
    const float* __restrict__ fw1, const float* __restrict__ fb1,
    const float* __restrict__ fw2, const float* __restrict__ fb2,
    float* __restrict__ x)
{
    const int bn    = blockIdx.x;
    const int bbase = (bn >> 7) << 7;       // b * 128
    const int tid   = threadIdx.x;
    const int w     = tid >> 6;
    const int lane  = tid & 63;
    const int lq    = lane >> 4;            // 0..3
    const int fq    = lane & 15;            // 0..15
    const int fbase = w * 64 + fq * 4;
    const int arow  = lane & 15;

    __shared__ __align__(16) unsigned short Hh[Kk][264];  // 25344 B
    __shared__ __align__(16) unsigned short Hl[Kk][264];  // 25344 B
    __shared__ __align__(16) float sfe[Kk][52];           // 9984 B
    __shared__ __align__(16) float agg_s[Ff];             // 1 KB
    __shared__ __align__(16) float sv_s[Ff];              // 1 KB
    __shared__ float scut[Kk];
    __shared__ int   snbr[Kk];

    // ---- gaussian expansion from distances (in-kernel, kills fexp traffic) ----
    {
        const float step = 5.0f / 49.0f;
        const float coeff = -0.5f / (step * step);
        for (int idx = tid; idx < Kk * Gg; idx += 256) {
            int k = idx / Gg, g = idx - k * Gg;
            float d = sd[bn * Kk + k];
            float dd = d - step * (float)g;
            sfe[k][g] = expf(coeff * dd * dd);
        }
    }
    if (tid < Kk) {
        scut[tid] = fcut[bn * Kk + tid];
        snbr[tid] = nbr[bn * Kk + tid];
    }
    __syncthreads();

    // ---- layer 1 (VALU): thread = rows [12*lq,+12) x cols [fbase,+4) ----
    {
        const int kb = lq * 12;
        float h1[12][4];
        const float4 b1q = LDG4(&b1[fbase]);
        #pragma unroll
        for (int rr = 0; rr < 12; ++rr) {
            h1[rr][0] = b1q.x; h1[rr][1] = b1q.y;
            h1[rr][2] = b1q.z; h1[rr][3] = b1q.w;
        }
        #pragma unroll 1
        for (int c = 0; c < 6; ++c) {
            const int g0 = c * 8;
            float4 wq[8];
            #pragma unroll
            for (int j = 0; j < 8; ++j)
                wq[j] = LDG4(&w1[(g0 + j) * Ff + fbase]);
            #pragma unroll
            for (int rr = 0; rr < 12; ++rr) {
                const float4 fe0 = LDG4(&sfe[kb + rr][g0]);
                const float4 fe1 = LDG4(&sfe[kb + rr][g0 + 4]);
                FMA4(h1[rr], fe0.x, wq[0]); FMA4(h1[rr], fe0.y, wq[1]);
                FMA4(h1[rr], fe0.z, wq[2]); FMA4(h1[rr], fe0.w, wq[3]);
                FMA4(h1[rr], fe1.x, wq[4]); FMA4(h1[rr], fe1.y, wq[5]);
                FMA4(h1[rr], fe1.z, wq[6]); FMA4(h1[rr], fe1.w, wq[7]);
            }
        }
        const float4 wt0 = LDG4(&w1[48 * Ff + fbase]);
        const float4 wt1 = LDG4(&w1[49 * Ff + fbase]);
        #pragma unroll
        for (int rr = 0; rr < 12; ++rr) {
            const float fa = sfe[kb + rr][48];
            const float fb = sfe[kb + rr][49];
            FMA4(h1[rr], fa, wt0);
            FMA4(h1[rr], fb, wt1);
            // ssp -> split bf16 hi/lo -> LDS
            float v0 = ssp_f(h1[rr][0]);
            float v1 = ssp_f(h1[rr][1]);
            float v2 = ssp_f(h1[rr][2]);
            float v3 = ssp_f(h1[rr][3]);
            unsigned short hh0 = f2bf(v0), hh1 = f2bf(v1), hh2 = f2bf(v2), hh3 = f2bf(v3);
            unsigned short ll0 = f2bf(v0 - bf2f(hh0));
            unsigned short ll1 = f2bf(v1 - bf2f(hh1));
            unsigned short ll2 = f2bf(v2 - bf2f(hh2));
            unsigned short ll3 = f2bf(v3 - bf2f(hh3));
            *reinterpret_cast<uint2*>(&Hh[kb + rr][fbase]) =
                make_uint2((unsigned)hh0 | ((unsigned)hh1 << 16),
                           (unsigned)hh2 | ((unsigned)hh3 << 16));
            *reinterpret_cast<uint2*>(&Hl[kb + rr][fbase]) =
                make_uint2((unsigned)ll0 | ((unsigned)ll1 << 16),
                           (unsigned)ll2 | ((unsigned)ll3 << 16));
        }
    }
    __syncthreads();

    // ---- layer 2 (MFMA): wave w = fout quarter [64w,64w+64) ----
    f32x4 acc[3][4];
    #pragma unroll
    for (int mt = 0; mt < 3; ++mt)
        #pragma unroll
        for (int nt = 0; nt < 4; ++nt)
            acc[mt][nt] = (f32x4){0.f, 0.f, 0.f, 0.f};

    const int kgrp = lq * 8;
    const unsigned short* bhp[4];
    const unsigned short* blp[4];
    #pragma unroll
    for (int nt = 0; nt < 4; ++nt) {
        const int n = w * 64 + nt * 16 + arow;
        bhp[nt] = whT + (size_t)n * Ff;
        blp[nt] = wlT + (size_t)n * Ff;
    }

    #pragma unroll 1
    for (int kk = 0; kk < 8; ++kk) {
        const int ko = kk * 32 + kgrp;
        bf16x8 ah[3], al[3], bh[4], bl[4];
        #pragma unroll
        for (int mt = 0; mt < 3; ++mt) {
            ah[mt] = *reinterpret_cast<const bf16x8*>(&Hh[mt * 16 + arow][ko]);
            al[mt] = *reinterpret_cast<const bf16x8*>(&Hl[mt * 16 + arow][ko]);
        }
        #pragma unroll
        for (int nt = 0; nt < 4; ++nt) {
            bh[nt] = *reinterpret_cast<const bf16x8*>(bhp[nt] + ko);
            bl[nt] = *reinterpret_cast<const bf16x8*>(blp[nt] + ko);
        }
        #pragma unroll
        for (int mt = 0; mt < 3; ++mt)
            #pragma unroll
            for (int nt = 0; nt < 4; ++nt) {
                acc[mt][nt] = MFMA_B16(ah[mt], bh[nt], acc[mt][nt]);
                acc[mt][nt] = MFMA_B16(ah[mt], bl[nt], acc[mt][nt]);
                acc[mt][nt] = MFMA_B16(al[mt], bh[nt], acc[mt][nt]);
            }
    }

    // ---- consume: cutoff + neighbor y gather + cross-row reduce ----
    float b2v[4];
    #pragma unroll
    for (int nt = 0; nt < 4; ++nt) b2v[nt] = b2[w * 64 + nt * 16 + arow];

    float aggp[4] = {0.f, 0.f, 0.f, 0.f};
    #pragma unroll
    for (int mt = 0; mt < 3; ++mt) {
        #pragma unroll
        for (int j = 0; j < 4; ++j) {
            const int r = mt * 16 + lq * 4 + j;     // D row = k index
            const float ct = scut[r];
            const int   nb = snbr[r];
            const float* yr = y + (size_t)(bbase + nb) * Ff + w * 64 + arow;
            #pragma unroll
            for (int nt = 0; nt < 4; ++nt)
                aggp[nt] = fmaf((acc[mt][nt][j] + b2v[nt]) * ct, yr[nt * 16], aggp[nt]);
        }
    }
    #pragma unroll
    for (int nt = 0; nt < 4; ++nt) {
        aggp[nt] += __shfl_xor(aggp[nt], 16);
        aggp[nt] += __shfl_xor(aggp[nt], 32);
    }
    if (lq == 0) {
        #pragma unroll
        for (int nt = 0; nt < 4; ++nt)
            agg_s[w * 64 + nt * 16 + arow] = aggp[nt];
    }
    __syncthreads();

    // ---- f2out matvec 1 (VALU, lq = h-quarter) ----
    {
        float p[4] = {0.f, 0.f, 0.f, 0.f};
        const int hb = lq * 64;
        #pragma unroll 1
        for (int c = 0; c < 8; ++c) {
            const int h0 = hb + c * 8;
            float4 wq[8];
            #pragma unroll
            for (int j = 0; j < 8; ++j)
                wq[j] = LDG4(&fw1[(h0 + j) * Ff + fbase]);
            const float4 a0 = LDG4(&agg_s[h0]);
            const float4 a1 = LDG4(&agg_s[h0 + 4]);
            FMA4(p, a0.x, wq[0]); FMA4(p, a0.y, wq[1]);
            FMA4(p, a0.z, wq[2]); FMA4(p, a0.w, wq[3]);
            FMA4(p, a1.x, wq[4]); FMA4(p, a1.y, wq[5]);
            FMA4(p, a1.z, wq[6]); FMA4(p, a1.w, wq[7]);
        }
        #pragma unroll
        for (int j = 0; j < 4; ++j) {
            p[j] += __shfl_xor(p[j], 16);
            p[j] += __shfl_xor(p[j], 32);
        }
        if (lq == 0) {
            const float4 fb1q = LDG4(&fb1[fbase]);
            float4 sv;
            sv.x = ssp_f(p[0] + fb1q.x); sv.y = ssp_f(p[1] + fb1q.y);
            sv.z = ssp_f(p[2] + fb1q.z); sv.w = ssp_f(p[3] + fb1q.w);
            ST4(&sv_s[fbase], sv);
        }
    }
    __syncthreads();

    // ---- f2out matvec 2 + residual ----
    {
        float p[4] = {0.f, 0.f, 0.f, 0.f};
        const int hb = lq * 64;
        #pragma unroll 1
        for (int c = 0; c < 8; ++c) {
            const int h0 = hb + c * 8;
            float4 wq[8];
            #pragma unroll
            for (int j = 0; j < 8; ++j)
                wq[j] = LDG4(&fw2[(h0 + j) * Ff + fbase]);
            const float4 a0 = LDG4(&sv_s[h0]);
            const float4 a1 = LDG4(&sv_s[h0 + 4]);
            FMA4(p, a0.x, wq[0]); FMA4(p, a0.y, wq[1]);
            FMA4(p, a0.z, wq[2]); FMA4(p, a0.w, wq[3]);
            FMA4(p, a1.x, wq[4]); FMA4(p, a1.y, wq[5]);
            FMA4(p, a1.z, wq[6]); FMA4(p, a1.w, wq[7]);
        }
        #pragma unroll
        for (int j = 0; j < 4; ++j) {
            p[j] += __shfl_xor(p[j], 16);
            p[j] += __shfl_xor(p[j], 32);
        }
        if (lq == 0) {
            const float4 fb2q = LDG4(&fb2[fbase]);
            float4 xv = LDG4(&x[bn * Ff + fbase]);
            xv.x += p[0] + fb2q.x;
            xv.y += p[1] + fb2q.y;
            xv.z += p[2] + fb2q.z;
            xv.w += p[3] + fb2q.w;
            ST4(&x[bn * Ff + fbase], xv);
        }
    }
}

// ---------------------------------------------------------------------------
// k_head: disp/frac/rep, predictor MLP, masked mean, new_cell, new_pos
// ---------------------------------------------------------------------------
__global__ __launch_bounds__(128) void k_head(
    const float* __restrict__ x, const float* __restrict__ pos,
    const float* __restrict__ cell, const float* __restrict__ amask,
    const float* __restrict__ fdw, const float* __restrict__ fdb,
    const float* __restrict__ pw1, const float* __restrict__ pb1,
    const float* __restrict__ pw2, const float* __restrict__ pb2,
    float* __restrict__ out_pos, float* __restrict__ out_cell)
{
    const int b = blockIdx.x;
    const int n = threadIdx.x;

    __shared__ float sinv[9];
    __shared__ float scell[9];
    __shared__ float snc[9];
    __shared__ float sred[Nn][10];

    if (n == 0) {
        float c[9];
        #pragma unroll
        for (int i = 0; i < 9; ++i) { c[i] = cell[b * 9 + i]; scell[i] = c[i]; }
        float det = c[0] * (c[4] * c[8] - c[5] * c[7])
                  - c[1] * (c[3] * c[8] - c[5] * c[6])
                  + c[2] * (c[3] * c[7] - c[4] * c[6]);
        float id = 1.0f / det;
        sinv[0] = (c[4] * c[8] - c[5] * c[7]) * id;
        sinv[1] = (c[2] * c[7] - c[1] * c[8]) * id;
        sinv[2] = (c[1] * c[5] - c[2] * c[4]) * id;
        sinv[3] = (c[5] * c[6] - c[3] * c[8]) * id;
        sinv[4] = (c[0] * c[8] - c[2] * c[6]) * id;
        sinv[5] = (c[2] * c[3] - c[0] * c[5]) * id;
        sinv[6] = (c[3] * c[7] - c[4] * c[6]) * id;
        sinv[7] = (c[1] * c[6] - c[0] * c[7]) * id;
        sinv[8] = (c[0] * c[4] - c[1] * c[3]) * id;
    }
    __syncthreads();

    float xv0 = 0.f, xv1 = 0.f, xv2 = 0.f;
    const int row = (b * Nn + n) * Ff;
    for (int ff = 0; ff < Ff; ++ff) {
        float xr = x[row + ff];
        xv0 = fmaf(xr, fdw[ff * 3 + 0], xv0);
        xv1 = fmaf(xr, fdw[ff * 3 + 1], xv1);
        xv2 = fmaf(xr, fdw[ff * 3 + 2], xv2);
    }
    float fr[3];
    float dsp[3] = {xv0, xv1, xv2};
    const float p0 = pos[(b * Nn + n) * 3 + 0];
    const float p1 = pos[(b * Nn + n) * 3 + 1];
    const float p2 = pos[(b * Nn + n) * 3 + 2];
    #pragma unroll
    for (int j = 0; j < 3; ++j) {
        float z = 10.0f * (dsp[j] + fdb[j]);
        float s = 1.0f / (1.0f + expf(-z));
        float fx = p0 * sinv[0 * 3 + j] + p1 * sinv[1 * 3 + j] + p2 * sinv[2 * 3 + j] + s;
        fr[j] = fx - floorf(fx);
    }

    float rep[3];
    #pragma unroll
    for (int j = 0; j < 3; ++j)
        rep[j] = fr[0] * scell[0 * 3 + j] + fr[1] * scell[1 * 3 + j] + fr[2] * scell[2 * 3 + j];

    float a6[6];
    #pragma unroll
    for (int i = 0; i < 6; ++i) {
        float uv = rep[0] * pw1[0 * 6 + i] + rep[1] * pw1[1 * 6 + i]
                 + rep[2] * pw1[2 * 6 + i] + pb1[i];
        a6[i] = ssp_f(uv);
    }
    float h9[9];
    #pragma unroll
    for (int o = 0; o < 9; ++o) {
        float uv = pb2[o];
        #pragma unroll
        for (int i = 0; i < 6; ++i) uv = fmaf(a6[i], pw2[i * 9 + o], uv);
        h9[o] = uv;
    }

    const float m = amask[b * Nn + n];
    #pragma unroll
    for (int o = 0; o < 9; ++o) sred[n][o] = h9[o] * m;
    sred[n][9] = m;
    __syncthreads();

    for (int s = 64; s >= 1; s >>= 1) {
        if (n < s) {
            #pragma unroll
            for (int o = 0; o < 10; ++o) sred[n][o] += sred[n + s][o];
        }
        __syncthreads();
    }

    if (n < 9) {
        float na = sred[0][9];
        float yo = sred[0][n] / na;
        float scale = 3.0f * powf(na, 1.0f / 3.0f);
        int r = n / 3, c = n - r * 3;
        float v = scale * (((r == c) ? 1.0f : 0.0f) + yo);
        snc[n] = v;
        out_cell[b * 9 + n] = v;
    }
    __syncthreads();

    #pragma unroll
    for (int j = 0; j < 3; ++j) {
        float v = fr[0] * snc[0 * 3 + j] + fr[1] * snc[1 * 3 + j] + fr[2] * snc[2 * 3 + j];
        out_pos[(b * Nn + n) * 3 + j] = v;
    }
}

// ---------------------------------------------------------------------------
extern "C" void kernel_launch(void* const* d_in, const int* in_sizes, int n_in,
                              void* d_out, int out_size, void* d_ws, size_t ws_size,
                              hipStream_t stream)
{
    const float* positions     = (const float*)d_in[0];
    const float* cell          = (const float*)d_in[1];
    const int*   atomic_nums   = (const int*)  d_in[2];
    const int*   neighbors     = (const int*)  d_in[3];
    const float* neighbor_mask = (const float*)d_in[4];
    const float* atom_mask     = (const float*)d_in[5];
    const float* embedding     = (const float*)d_in[6];
    const float* filt_w1       = (const float*)d_in[7];
    const float* filt_b1       = (const float*)d_in[8];
    const float* filt_w2       = (const float*)d_in[9];
    const float* filt_b2       = (const float*)d_in[10];
    const float* in2f_w        = (const float*)d_in[11];
    const float* f2out_w1      = (const float*)d_in[12];
    const float* f2out_b1      = (const float*)d_in[13];
    const float* f2out_w2      = (const float*)d_in[14];
    const float* f2out_b2      = (const float*)d_in[15];
    const float* fd_w          = (const float*)d_in[16];
    const float* fd_b          = (const float*)d_in[17];
    const float* pred_w1       = (const float*)d_in[18];
    const float* pred_b1       = (const float*)d_in[19];
    const float* pred_w2       = (const float*)d_in[20];
    const float* pred_b2       = (const float*)d_in[21];

    float* ws   = (float*)d_ws;
    float* x    = ws;                          // 1048576 f32
    float* y    = x + Bb * Nn * Ff;            // 1048576 f32
    float* sd   = y + Bb * Nn * Ff;            // 196608 f32
    float* fcut = sd + Bb * Nn * Kk;           // 196608 f32
    unsigned short* whT = (unsigned short*)(fcut + Bb * Nn * Kk);  // 3*65536 us
    unsigned short* wlT = whT + Tt * Ff * Ff;                       // 3*65536 us

    float* out_pos  = (float*)d_out;
    float* out_cell = out_pos + Bb * Nn * 3;

    const int BN = Bb * Nn;

    k_setup<<<BN, 256, 0, stream>>>(positions, atomic_nums, neighbors,
                                    neighbor_mask, embedding, x, sd, fcut);
    k_wsplit<<<Tt * Ff, 256, 0, stream>>>(filt_w2, whT, wlT);

    for (int t = 0; t < Tt; ++t) {
        k_y4<<<BN / 4, 256, 0, stream>>>(x, in2f_w + (size_t)t * Ff * Ff, y);
        k_aggm<<<BN, 256, 0, stream>>>(sd, fcut, neighbors, y,
                                       filt_w1 + (size_t)t * Gg * Ff,
                                       filt_b1 + (size_t)t * Ff,
                                       whT + (size_t)t * Ff * Ff,
                                       wlT + (size_t)t * Ff * Ff,
                                       filt_b2 + (size_t)t * Ff,
                                       f2out_w1 + (size_t)t * Ff * Ff,
                                       f2out_b1 + (size_t)t * Ff,
                                       f2out_w2 + (size_t)t * Ff * Ff,
                                       f2out_b2 + (size_t)t * Ff,
                                       x);
    }

    k_head<<<Bb, 128, 0, stream>>>(x, positions, cell, atom_mask,
                                   fd_w, fd_b, pred_w1, pred_b1, pred_w2, pred_b2,
                                   out_pos, out_cell);
}